// Round 6
// baseline (261.013 us; speedup 1.0000x reference)
//
#include <hip/hip_runtime.h>
#include <hip/hip_fp16.h>

using i32x4  = __attribute__((ext_vector_type(4)))  int;
using i32x16 = __attribute__((ext_vector_type(16))) int;

static constexpr int M  = 4 * 2048;   // 8192 rows (B*S)
static constexpr int N  = 4096;       // OUT_F
static constexpr int K  = 4096;       // IN_F
static constexpr int BM = 256, BN = 256, BK = 64;
static constexpr int NT = K / BK;       // 64 K-tiles
static constexpr int TILE = BM * BK;    // 16384 bytes per packed int8 tile

// ---------------- pack kernels: int32 -> blocked int8 tiles in d_ws ----------
// tile layout (16 KB): [kg(4)][row(256)][16 bytes of k] -> off = kg*4096 + row*16
// wa: [M/256][NT][tile], wb: [N/256][NT][tile] (wb transposed: granule bytes walk k)

__device__ __forceinline__ unsigned pack4(i32x4 v) {
  return (unsigned)((v.x & 255) | ((v.y & 255) << 8) | ((v.z & 255) << 16) | (v.w << 24));
}

__global__ __launch_bounds__(256) void pack_x_kernel(const int* __restrict__ x,
                                                     unsigned char* __restrict__ wa) {
  unsigned g = blockIdx.x * 256 + threadIdx.x;   // dest 16B granule id, < M*K/16
  unsigned row = g & 255;
  unsigned kg  = (g >> 8) & 3;
  unsigned kt  = (g >> 10) & 63;
  unsigned br  = g >> 16;
  const int* src = x + ((size_t)(br * 256 + row) * K + kt * 64 + kg * 16);
  i32x4 v0 = *(const i32x4*)(src + 0);
  i32x4 v1 = *(const i32x4*)(src + 4);
  i32x4 v2 = *(const i32x4*)(src + 8);
  i32x4 v3 = *(const i32x4*)(src + 12);
  i32x4 d;
  d.x = (int)pack4(v0); d.y = (int)pack4(v1); d.z = (int)pack4(v2); d.w = (int)pack4(v3);
  *(i32x4*)(wa + (size_t)g * 16) = d;
}

__global__ __launch_bounds__(256) void pack_w_kernel(const int* __restrict__ w,
                                                     unsigned char* __restrict__ wb) {
  unsigned g = blockIdx.x * 256 + threadIdx.x;   // dest 16B granule id, < N*K/16
  unsigned col = g & 255;
  unsigned kg  = (g >> 8) & 3;
  unsigned kt  = (g >> 10) & 63;
  unsigned bn  = g >> 16;
  unsigned n   = bn * 256 + col;
  unsigned k0  = kt * 64 + kg * 16;
  const int* src = w + (size_t)k0 * N + n;
  i32x4 d;
#pragma unroll
  for (int j = 0; j < 4; ++j) {
    int b0 = src[(size_t)(j * 4 + 0) * N];
    int b1 = src[(size_t)(j * 4 + 1) * N];
    int b2 = src[(size_t)(j * 4 + 2) * N];
    int b3 = src[(size_t)(j * 4 + 3) * N];
    d[j] = (b0 & 255) | ((b1 & 255) << 8) | ((b2 & 255) << 16) | (b3 << 24);
  }
  *(i32x4*)(wb + (size_t)g * 16) = d;
}

// ---- GEMM: 4 waves, wave tile 128x128 (4x4 acc of 32x32), triple-buffer ----

__device__ __forceinline__ void gload_lds16(const void* g, void* l) {
  __builtin_amdgcn_global_load_lds((const __attribute__((address_space(1))) unsigned int*)g,
                                   (__attribute__((address_space(3))) unsigned int*)l,
                                   16, 0, 0);
}

__global__ __launch_bounds__(256, 1) void gemm_i8(const unsigned char* __restrict__ wa,
                                                  const unsigned char* __restrict__ wb,
                                                  const __half* __restrict__ bias,
                                                  const float* __restrict__ alphaP,
                                                  float* __restrict__ out) {
  __shared__ __align__(16) unsigned char As[3][TILE];   // 48 KB
  __shared__ __align__(16) unsigned char Bs[3][TILE];   // 48 KB

  const int tid  = threadIdx.x;
  const int lane = tid & 63;
  const int w    = tid >> 6;            // wave 0..3
  const int wr   = w >> 1, wc = w & 1;  // 2 x 2 wave grid; wave tile 128x128
  const int l31  = lane & 31;
  const int kgl  = lane >> 5;

  // swizzle: each XCD (bid&7) owns 2 bc panels -> B stays L2-resident
  const int bid = blockIdx.x;
  const int i   = bid >> 3;
  const int bc  = (bid & 7) * 2 + (i >> 5);   // 0..15
  const int br  = i & 31;                     // 0..31

  const unsigned char* ga = wa + (size_t)br * NT * TILE;
  const unsigned char* gb = wb + (size_t)bc * NT * TILE;

  // wave w stages 4KB of A and 4KB of B per tile (8 gload instrs)
  auto stage = [&](int buf, int t) {
    const unsigned char* at = ga + (size_t)t * TILE;
    const unsigned char* bt = gb + (size_t)t * TILE;
#pragma unroll
    for (int j = 0; j < 4; ++j) {
      gload_lds16(at + w * 4096 + j * 1024 + lane * 16, &As[buf][w * 4096 + j * 1024]);
      gload_lds16(bt + w * 4096 + j * 1024 + lane * 16, &Bs[buf][w * 4096 + j * 1024]);
    }
  };

  stage(0, 0);
  stage(1, 1);
  asm volatile("s_waitcnt vmcnt(8)" ::: "memory");   // tile 0 resident, tile 1 in flight
  __builtin_amdgcn_s_barrier();

  i32x16 acc[4][4] = {};

  const int arow = wr * 128 + l31;      // A frag row base (per lane)
  const int bcol = wc * 128 + l31;      // B frag col base (per lane)

  for (int t = 0; t < NT; ++t) {
    const unsigned char* Ab = &As[t % 3][0] + kgl * 4096;
    const unsigned char* Bb = &Bs[t % 3][0] + kgl * 4096;

    if (t + 2 < NT) stage((t + 2) % 3, t + 2);

    // kc0 fragments
    i32x4 a0 = *(const i32x4*)(Ab + (arow +  0) * 16);
    i32x4 a1 = *(const i32x4*)(Ab + (arow + 32) * 16);
    i32x4 a2 = *(const i32x4*)(Ab + (arow + 64) * 16);
    i32x4 a3 = *(const i32x4*)(Ab + (arow + 96) * 16);
    i32x4 b0 = *(const i32x4*)(Bb + (bcol +  0) * 16);
    i32x4 b1 = *(const i32x4*)(Bb + (bcol + 32) * 16);
    i32x4 b2 = *(const i32x4*)(Bb + (bcol + 64) * 16);
    i32x4 b3 = *(const i32x4*)(Bb + (bcol + 96) * 16);

#define MFMA16(A0, A1, A2, A3, B0, B1, B2, B3)                                 \
    acc[0][0] = __builtin_amdgcn_mfma_i32_32x32x32_i8(A0, B0, acc[0][0], 0,0,0); \
    acc[0][1] = __builtin_amdgcn_mfma_i32_32x32x32_i8(A0, B1, acc[0][1], 0,0,0); \
    acc[0][2] = __builtin_amdgcn_mfma_i32_32x32x32_i8(A0, B2, acc[0][2], 0,0,0); \
    acc[0][3] = __builtin_amdgcn_mfma_i32_32x32x32_i8(A0, B3, acc[0][3], 0,0,0); \
    acc[1][0] = __builtin_amdgcn_mfma_i32_32x32x32_i8(A1, B0, acc[1][0], 0,0,0); \
    acc[1][1] = __builtin_amdgcn_mfma_i32_32x32x32_i8(A1, B1, acc[1][1], 0,0,0); \
    acc[1][2] = __builtin_amdgcn_mfma_i32_32x32x32_i8(A1, B2, acc[1][2], 0,0,0); \
    acc[1][3] = __builtin_amdgcn_mfma_i32_32x32x32_i8(A1, B3, acc[1][3], 0,0,0); \
    acc[2][0] = __builtin_amdgcn_mfma_i32_32x32x32_i8(A2, B0, acc[2][0], 0,0,0); \
    acc[2][1] = __builtin_amdgcn_mfma_i32_32x32x32_i8(A2, B1, acc[2][1], 0,0,0); \
    acc[2][2] = __builtin_amdgcn_mfma_i32_32x32x32_i8(A2, B2, acc[2][2], 0,0,0); \
    acc[2][3] = __builtin_amdgcn_mfma_i32_32x32x32_i8(A2, B3, acc[2][3], 0,0,0); \
    acc[3][0] = __builtin_amdgcn_mfma_i32_32x32x32_i8(A3, B0, acc[3][0], 0,0,0); \
    acc[3][1] = __builtin_amdgcn_mfma_i32_32x32x32_i8(A3, B1, acc[3][1], 0,0,0); \
    acc[3][2] = __builtin_amdgcn_mfma_i32_32x32x32_i8(A3, B2, acc[3][2], 0,0,0); \
    acc[3][3] = __builtin_amdgcn_mfma_i32_32x32x32_i8(A3, B3, acc[3][3], 0,0,0)

    MFMA16(a0, a1, a2, a3, b0, b1, b2, b3);

    // kc1 fragments (reuse registers)
    a0 = *(const i32x4*)(Ab + 8192 + (arow +  0) * 16);
    a1 = *(const i32x4*)(Ab + 8192 + (arow + 32) * 16);
    a2 = *(const i32x4*)(Ab + 8192 + (arow + 64) * 16);
    a3 = *(const i32x4*)(Ab + 8192 + (arow + 96) * 16);
    b0 = *(const i32x4*)(Bb + 8192 + (bcol +  0) * 16);
    b1 = *(const i32x4*)(Bb + 8192 + (bcol + 32) * 16);
    b2 = *(const i32x4*)(Bb + 8192 + (bcol + 64) * 16);
    b3 = *(const i32x4*)(Bb + 8192 + (bcol + 96) * 16);

    MFMA16(a0, a1, a2, a3, b0, b1, b2, b3);
#undef MFMA16

    // tile t+1 residency; keep t+2's 8 loads in flight (never 0 mid-loop)
    if (t + 2 < NT)      asm volatile("s_waitcnt vmcnt(8)" ::: "memory");
    else if (t + 1 < NT) asm volatile("s_waitcnt vmcnt(0)" ::: "memory");
    __builtin_amdgcn_s_barrier();
  }

  // epilogue: C/D layout col=lane&31, row=(r&3)+8*(r>>2)+4*(lane>>5)
  const float alpha = *alphaP;
  const int row0 = br * 256 + wr * 128 + 4 * kgl;
  const int col0 = bc * 256 + wc * 128 + l31;
#pragma unroll
  for (int ni = 0; ni < 4; ++ni) {
    const int col = col0 + ni * 32;
    const float bf = __half2float(bias[col]);
#pragma unroll
    for (int mi = 0; mi < 4; ++mi) {
#pragma unroll
      for (int r = 0; r < 16; ++r) {
        const int row = row0 + mi * 32 + (r & 3) + 8 * (r >> 2);
        out[(size_t)row * N + col] = ((float)acc[mi][ni][r] + bf) * alpha;
      }
    }
  }
}

extern "C" void kernel_launch(void* const* d_in, const int* in_sizes, int n_in,
                              void* d_out, int out_size, void* d_ws, size_t ws_size,
                              hipStream_t stream) {
  const int*    x     = (const int*)d_in[0];
  const int*    wgt   = (const int*)d_in[1];
  const __half* bias  = (const __half*)d_in[2];
  const float*  alpha = (const float*)d_in[3];
  float*        out   = (float*)d_out;

  // workspace: packed A (32 MB) + packed B (16 MB) = 48 MB
  unsigned char* wa = (unsigned char*)d_ws;
  unsigned char* wb = wa + (size_t)M * K;

  pack_x_kernel<<<(M * (size_t)K / 16) / 256, 256, 0, stream>>>(x, wa);
  pack_w_kernel<<<(N * (size_t)K / 16) / 256, 256, 0, stream>>>(wgt, wb);

  dim3 grid((M / BM) * (N / BN));   // 512 blocks, 1 block/CU resident
  gemm_i8<<<grid, 256, 0, stream>>>(wa, wb, bias, alpha, out);
}

// Round 7
// 242.378 us; speedup vs baseline: 1.0769x; 1.0769x over previous
//
#include <hip/hip_runtime.h>
#include <hip/hip_fp16.h>

using i32x4  = __attribute__((ext_vector_type(4)))  int;
using i32x16 = __attribute__((ext_vector_type(16))) int;

static constexpr int M  = 4 * 2048;   // 8192 rows (B*S)
static constexpr int N  = 4096;       // OUT_F
static constexpr int K  = 4096;       // IN_F
static constexpr int BM = 256, BN = 128, BK = 64;
static constexpr int NT = K / BK;         // 64 K-tiles
static constexpr int ATILE = BM * BK;     // 16384 B packed A tile
static constexpr int BTILE = BN * BK;     //  8192 B packed B tile

// ---------------- pack kernels: int32 -> blocked int8 tiles in d_ws ----------
// A tile (16 KB): [kg(4)][row(256)][16B]   wa: [M/256][NT][ATILE]
// B tile ( 8 KB): [kg(4)][col(128)][16B]   wb: [N/128][NT][BTILE] (transposed)

__device__ __forceinline__ unsigned pack4(i32x4 v) {
  return (unsigned)((v.x & 255) | ((v.y & 255) << 8) | ((v.z & 255) << 16) | (v.w << 24));
}

__global__ __launch_bounds__(256) void pack_x_kernel(const int* __restrict__ x,
                                                     unsigned char* __restrict__ wa) {
  unsigned g = blockIdx.x * 256 + threadIdx.x;   // dest 16B granule id, < M*K/16
  unsigned row = g & 255;
  unsigned kg  = (g >> 8) & 3;
  unsigned kt  = (g >> 10) & 63;
  unsigned br  = g >> 16;
  const int* src = x + ((size_t)(br * 256 + row) * K + kt * 64 + kg * 16);
  i32x4 v0 = *(const i32x4*)(src + 0);
  i32x4 v1 = *(const i32x4*)(src + 4);
  i32x4 v2 = *(const i32x4*)(src + 8);
  i32x4 v3 = *(const i32x4*)(src + 12);
  i32x4 d;
  d.x = (int)pack4(v0); d.y = (int)pack4(v1); d.z = (int)pack4(v2); d.w = (int)pack4(v3);
  *(i32x4*)(wa + (size_t)g * 16) = d;
}

__global__ __launch_bounds__(256) void pack_w_kernel(const int* __restrict__ w,
                                                     unsigned char* __restrict__ wb) {
  unsigned g = blockIdx.x * 256 + threadIdx.x;   // dest 16B granule id, < N*K/16
  unsigned col = g & 127;
  unsigned kg  = (g >> 7) & 3;
  unsigned kt  = (g >> 9) & 63;
  unsigned bn  = g >> 15;
  unsigned n   = bn * 128 + col;
  unsigned k0  = kt * 64 + kg * 16;
  const int* src = w + (size_t)k0 * N + n;
  i32x4 d;
#pragma unroll
  for (int j = 0; j < 4; ++j) {
    int b0 = src[(size_t)(j * 4 + 0) * N];
    int b1 = src[(size_t)(j * 4 + 1) * N];
    int b2 = src[(size_t)(j * 4 + 2) * N];
    int b3 = src[(size_t)(j * 4 + 3) * N];
    d[j] = (b0 & 255) | ((b1 & 255) << 8) | ((b2 & 255) << 16) | (b3 << 24);
  }
  *(i32x4*)(wb + (size_t)g * 16) = d;
}

// -- GEMM: 256x128 block, 4 waves (2x2), 2 blocks/CU, triple-buffer, vmcnt(6) --

__device__ __forceinline__ void gload_lds16(const void* g, void* l) {
  __builtin_amdgcn_global_load_lds((const __attribute__((address_space(1))) unsigned int*)g,
                                   (__attribute__((address_space(3))) unsigned int*)l,
                                   16, 0, 0);
}

__global__ __launch_bounds__(256, 2) void gemm_i8(const unsigned char* __restrict__ wa,
                                                  const unsigned char* __restrict__ wb,
                                                  const __half* __restrict__ bias,
                                                  const float* __restrict__ alphaP,
                                                  float* __restrict__ out) {
  __shared__ __align__(16) unsigned char As[3][ATILE];   // 48 KB
  __shared__ __align__(16) unsigned char Bs[3][BTILE];   // 24 KB  -> 72 KB total

  const int tid  = threadIdx.x;
  const int lane = tid & 63;
  const int w    = tid >> 6;            // wave 0..3
  const int wr   = w >> 1, wc = w & 1;  // 2 x 2 wave grid; wave tile 128x64
  const int l31  = lane & 31;
  const int kgl  = lane >> 5;

  const int bc = blockIdx.x;            // 0..31 (fast: neighbors share A panel)
  const int br = blockIdx.y;            // 0..31

  const unsigned char* ga = wa + (size_t)br * NT * ATILE;
  const unsigned char* gb = wb + (size_t)bc * NT * BTILE;

  // 6 gloads/wave/tile: 4 for A (16 KB / 4 waves), 2 for B (8 KB / 4 waves)
  auto stage = [&](int buf, int t) {
    const unsigned char* at = ga + (size_t)t * ATILE;
    const unsigned char* bt = gb + (size_t)t * BTILE;
#pragma unroll
    for (int j = 0; j < 4; ++j)
      gload_lds16(at + (w * 4 + j) * 1024 + lane * 16, &As[buf][(w * 4 + j) * 1024]);
#pragma unroll
    for (int j = 0; j < 2; ++j)
      gload_lds16(bt + (w * 2 + j) * 1024 + lane * 16, &Bs[buf][(w * 2 + j) * 1024]);
  };

  stage(0, 0);
  stage(1, 1);
  asm volatile("s_waitcnt vmcnt(6)" ::: "memory");   // tile 0 resident, tile 1 in flight
  __builtin_amdgcn_s_barrier();

  i32x16 acc[4][2] = {};

  const int arow = wr * 128 + l31;      // A frag row base (per lane)
  const int bcol = wc * 64 + l31;       // B frag col base (per lane)

  for (int t = 0; t < NT; ++t) {
    if (t + 2 < NT) stage((t + 2) % 3, t + 2);   // issue prefetch first

    const unsigned char* Ab = &As[t % 3][0] + kgl * 4096;
    const unsigned char* Bb = &Bs[t % 3][0] + kgl * 2048;

#pragma unroll
    for (int kc = 0; kc < 2; ++kc) {      // kc1 at +8192 (A) / +4096 (B)
      const unsigned char* Ap = Ab + kc * 8192;
      const unsigned char* Bp = Bb + kc * 4096;
      i32x4 a0 = *(const i32x4*)(Ap + (arow +  0) * 16);
      i32x4 a1 = *(const i32x4*)(Ap + (arow + 32) * 16);
      i32x4 a2 = *(const i32x4*)(Ap + (arow + 64) * 16);
      i32x4 a3 = *(const i32x4*)(Ap + (arow + 96) * 16);
      i32x4 b0 = *(const i32x4*)(Bp + (bcol +  0) * 16);
      i32x4 b1 = *(const i32x4*)(Bp + (bcol + 32) * 16);
      acc[0][0] = __builtin_amdgcn_mfma_i32_32x32x32_i8(a0, b0, acc[0][0], 0, 0, 0);
      acc[0][1] = __builtin_amdgcn_mfma_i32_32x32x32_i8(a0, b1, acc[0][1], 0, 0, 0);
      acc[1][0] = __builtin_amdgcn_mfma_i32_32x32x32_i8(a1, b0, acc[1][0], 0, 0, 0);
      acc[1][1] = __builtin_amdgcn_mfma_i32_32x32x32_i8(a1, b1, acc[1][1], 0, 0, 0);
      acc[2][0] = __builtin_amdgcn_mfma_i32_32x32x32_i8(a2, b0, acc[2][0], 0, 0, 0);
      acc[2][1] = __builtin_amdgcn_mfma_i32_32x32x32_i8(a2, b1, acc[2][1], 0, 0, 0);
      acc[3][0] = __builtin_amdgcn_mfma_i32_32x32x32_i8(a3, b0, acc[3][0], 0, 0, 0);
      acc[3][1] = __builtin_amdgcn_mfma_i32_32x32x32_i8(a3, b1, acc[3][1], 0, 0, 0);
    }

    // tile t+1 residency (<=6 outstanding == only t+2's loads); never 0 mid-loop
    if (t + 2 < NT)      asm volatile("s_waitcnt vmcnt(6)" ::: "memory");
    else if (t + 1 < NT) asm volatile("s_waitcnt vmcnt(0)" ::: "memory");
    __builtin_amdgcn_s_barrier();
  }

  // epilogue: C/D layout col=lane&31, row=(r&3)+8*(r>>2)+4*(lane>>5)
  const float alpha = *alphaP;
  const int row0 = br * 256 + wr * 128 + 4 * kgl;
  const int col0 = bc * 128 + wc * 64 + l31;
#pragma unroll
  for (int ni = 0; ni < 2; ++ni) {
    const int col = col0 + ni * 32;
    const float bf = __half2float(bias[col]);
#pragma unroll
    for (int mi = 0; mi < 4; ++mi) {
#pragma unroll
      for (int r = 0; r < 16; ++r) {
        const int row = row0 + mi * 32 + (r & 3) + 8 * (r >> 2);
        out[(size_t)row * N + col] = ((float)acc[mi][ni][r] + bf) * alpha;
      }
    }
  }
}

extern "C" void kernel_launch(void* const* d_in, const int* in_sizes, int n_in,
                              void* d_out, int out_size, void* d_ws, size_t ws_size,
                              hipStream_t stream) {
  const int*    x     = (const int*)d_in[0];
  const int*    wgt   = (const int*)d_in[1];
  const __half* bias  = (const __half*)d_in[2];
  const float*  alpha = (const float*)d_in[3];
  float*        out   = (float*)d_out;

  // workspace: packed A (32 MB) + packed B (16 MB) = 48 MB
  unsigned char* wa = (unsigned char*)d_ws;
  unsigned char* wb = wa + (size_t)M * K;

  pack_x_kernel<<<(M * (size_t)K / 16) / 256, 256, 0, stream>>>(x, wa);
  pack_w_kernel<<<(N * (size_t)K / 16) / 256, 256, 0, stream>>>(wgt, wb);

  dim3 grid(N / BN, M / BM);   // 32 x 32 = 1024 blocks, 2 resident/CU
  gemm_i8<<<grid, 256, 0, stream>>>(wa, wb, bias, alpha, out);
}

// Round 8
// 230.439 us; speedup vs baseline: 1.1327x; 1.0518x over previous
//
#include <hip/hip_runtime.h>
#include <hip/hip_fp16.h>

using i32x4  = __attribute__((ext_vector_type(4)))  int;
using i32x16 = __attribute__((ext_vector_type(16))) int;

static constexpr int M  = 4 * 2048;   // 8192 rows (B*S)
static constexpr int N  = 4096;       // OUT_F
static constexpr int K  = 4096;       // IN_F
static constexpr int BM = 128, BN = 128, BK = 64;
static constexpr int NT = K / BK;     // 64 K-tiles
static constexpr int TILE = BM * BK;  // 8192 bytes per packed int8 tile

// ---------------- pack kernels: int32 -> blocked int8 tiles in d_ws ----------
// tile layout (8 KB): [kg(4)][row(128)][16 bytes of k] -> byte off = kg*2048 + row*16
// wa: [M/128][NT][tile], wb: [N/128][NT][tile] (wb transposed: granule bytes walk k)

__device__ __forceinline__ unsigned pack4(i32x4 v) {
  return (unsigned)((v.x & 255) | ((v.y & 255) << 8) | ((v.z & 255) << 16) | (v.w << 24));
}

__global__ __launch_bounds__(256) void pack_x_kernel(const int* __restrict__ x,
                                                     unsigned char* __restrict__ wa) {
  unsigned g = blockIdx.x * 256 + threadIdx.x;     // dest 16B granule id, < M*K/16
  unsigned tile = g >> 9, gt = g & 511;
  unsigned kg = gt >> 7, row = gt & 127;
  unsigned br = tile >> 6, kt = tile & 63;
  const int* src = x + ((size_t)(br * 128 + row) * K + kt * 64 + kg * 16);
  i32x4 v0 = *(const i32x4*)(src + 0);
  i32x4 v1 = *(const i32x4*)(src + 4);
  i32x4 v2 = *(const i32x4*)(src + 8);
  i32x4 v3 = *(const i32x4*)(src + 12);
  i32x4 d;
  d.x = (int)pack4(v0); d.y = (int)pack4(v1); d.z = (int)pack4(v2); d.w = (int)pack4(v3);
  *(i32x4*)(wa + (size_t)g * 16) = d;
}

__global__ __launch_bounds__(256) void pack_w_kernel(const int* __restrict__ w,
                                                     unsigned char* __restrict__ wb) {
  unsigned g = blockIdx.x * 256 + threadIdx.x;     // dest 16B granule id, < N*K/16
  unsigned tile = g >> 9, gt = g & 511;
  unsigned kg = gt >> 7, col = gt & 127;
  unsigned bn = tile >> 6, kt = tile & 63;
  unsigned n  = bn * 128 + col;
  unsigned k0 = kt * 64 + kg * 16;
  const int* src = w + (size_t)k0 * N + n;
  i32x4 d;
#pragma unroll
  for (int j = 0; j < 4; ++j) {
    int b0 = src[(size_t)(j * 4 + 0) * N];
    int b1 = src[(size_t)(j * 4 + 1) * N];
    int b2 = src[(size_t)(j * 4 + 2) * N];
    int b3 = src[(size_t)(j * 4 + 3) * N];
    d[j] = (b0 & 255) | ((b1 & 255) << 8) | ((b2 & 255) << 16) | (b3 << 24);
  }
  *(i32x4*)(wb + (size_t)g * 16) = d;
}

// -- GEMM: 128x128, 4 waves (2x2), REG-STAGED LDS (no global_load_lds), dbuf --

__global__ __launch_bounds__(256) void gemm_i8(const unsigned char* __restrict__ wa,
                                               const unsigned char* __restrict__ wb,
                                               const __half* __restrict__ bias,
                                               const float* __restrict__ alphaP,
                                               float* __restrict__ out) {
  __shared__ __align__(16) unsigned char As[2][TILE];   // 16 KB
  __shared__ __align__(16) unsigned char Bs[2][TILE];   // 16 KB -> 32 KB total

  const int tid  = threadIdx.x;
  const int lane = tid & 63;
  const int w    = tid >> 6;            // wave 0..3
  const int wr   = w >> 1, wc = w & 1;  // 2 x 2 wave grid; wave tile 64x64
  const int l31  = lane & 31;
  const int kgl  = lane >> 5;

  const int bc = blockIdx.x;            // 0..31 (fast: neighbors share A panel)
  const int br = blockIdx.y;            // 0..63

  const unsigned char* ga = wa + (size_t)br * NT * TILE;
  const unsigned char* gb = wb + (size_t)bc * NT * TILE;

  // reg staging: 4 x 16B per thread per tile (A: granules tid, tid+256; B same)
  i32x4 s0, s1, s2, s3;

#define GLOAD(T) do {                                                \
    const i32x4* ap = (const i32x4*)(ga + (size_t)(T) * TILE);       \
    const i32x4* bp = (const i32x4*)(gb + (size_t)(T) * TILE);       \
    s0 = ap[tid]; s1 = ap[tid + 256];                                \
    s2 = bp[tid]; s3 = bp[tid + 256];                                \
  } while (0)

#define SWRITE(BUF) do {                                             \
    i32x4* aw = (i32x4*)&As[BUF][0];                                 \
    i32x4* bw = (i32x4*)&Bs[BUF][0];                                 \
    aw[tid] = s0; aw[tid + 256] = s1;                                \
    bw[tid] = s2; bw[tid + 256] = s3;                                \
  } while (0)

  GLOAD(0);
  SWRITE(0);          // compiler inserts vmcnt before the ds_writes
  __syncthreads();

  i32x16 acc[2][2] = {};

  const int arow = wr * 64 + l31;       // A frag row base (per lane)
  const int bcol = wc * 64 + l31;       // B frag col base (per lane)

  for (int t = 0; t < NT; ++t) {
    const int cur = t & 1;
    if (t + 1 < NT) GLOAD(t + 1);       // issue early: latency hides under MFMA

    const unsigned char* Ab = &As[cur][0] + kgl * 2048;
    const unsigned char* Bb = &Bs[cur][0] + kgl * 2048;
#pragma unroll
    for (int kc = 0; kc < 2; ++kc) {    // kg = kc*2 + kgl -> +kc*4096
      const unsigned char* Ap = Ab + kc * 4096;
      const unsigned char* Bp = Bb + kc * 4096;
      i32x4 a0 = *(const i32x4*)(Ap + (arow +  0) * 16);
      i32x4 a1 = *(const i32x4*)(Ap + (arow + 32) * 16);
      i32x4 b0 = *(const i32x4*)(Bp + (bcol +  0) * 16);
      i32x4 b1 = *(const i32x4*)(Bp + (bcol + 32) * 16);
      acc[0][0] = __builtin_amdgcn_mfma_i32_32x32x32_i8(a0, b0, acc[0][0], 0, 0, 0);
      acc[0][1] = __builtin_amdgcn_mfma_i32_32x32x32_i8(a0, b1, acc[0][1], 0, 0, 0);
      acc[1][0] = __builtin_amdgcn_mfma_i32_32x32x32_i8(a1, b0, acc[1][0], 0, 0, 0);
      acc[1][1] = __builtin_amdgcn_mfma_i32_32x32x32_i8(a1, b1, acc[1][1], 0, 0, 0);
    }

    // fence: keep gload issue + frag reads + MFMAs ABOVE; vmcnt-wait + ds_write BELOW
    __builtin_amdgcn_sched_barrier(0);
    if (t + 1 < NT) SWRITE(cur ^ 1);
    __syncthreads();
  }

  // epilogue: C/D layout col=lane&31, row=(r&3)+8*(r>>2)+4*(lane>>5)
  const float alpha = *alphaP;
  const int row0 = br * 128 + wr * 64 + 4 * kgl;
  const int col0 = bc * 128 + wc * 64 + l31;
#pragma unroll
  for (int ni = 0; ni < 2; ++ni) {
    const int col = col0 + ni * 32;
    const float bf = __half2float(bias[col]);
#pragma unroll
    for (int mi = 0; mi < 2; ++mi) {
#pragma unroll
      for (int r = 0; r < 16; ++r) {
        const int row = row0 + mi * 32 + (r & 3) + 8 * (r >> 2);
        out[(size_t)row * N + col] = ((float)acc[mi][ni][r] + bf) * alpha;
      }
    }
  }
#undef GLOAD
#undef SWRITE
}

extern "C" void kernel_launch(void* const* d_in, const int* in_sizes, int n_in,
                              void* d_out, int out_size, void* d_ws, size_t ws_size,
                              hipStream_t stream) {
  const int*    x     = (const int*)d_in[0];
  const int*    wgt   = (const int*)d_in[1];
  const __half* bias  = (const __half*)d_in[2];
  const float*  alpha = (const float*)d_in[3];
  float*        out   = (float*)d_out;

  // workspace: packed A (32 MB) + packed B (16 MB) = 48 MB
  unsigned char* wa = (unsigned char*)d_ws;
  unsigned char* wb = wa + (size_t)M * K;

  pack_x_kernel<<<(M * (size_t)K / 16) / 256, 256, 0, stream>>>(x, wa);
  pack_w_kernel<<<(N * (size_t)K / 16) / 256, 256, 0, stream>>>(wgt, wb);

  dim3 grid(N / BN, M / BM);   // 32 x 64 = 2048 blocks, ~3 resident/CU
  gemm_i8<<<grid, 256, 0, stream>>>(wa, wb, bias, alpha, out);
}

// Round 9
// 229.153 us; speedup vs baseline: 1.1390x; 1.0056x over previous
//
#include <hip/hip_runtime.h>
#include <hip/hip_fp16.h>

using i32x4  = __attribute__((ext_vector_type(4)))  int;
using i32x16 = __attribute__((ext_vector_type(16))) int;

static constexpr int M  = 4 * 2048;   // 8192 rows (B*S)
static constexpr int N  = 4096;       // OUT_F
static constexpr int K  = 4096;       // IN_F
static constexpr int BM = 256, BN = 128, BK = 64;
static constexpr int NT = K / BK;         // 64 K-tiles
static constexpr int ATILE = BM * BK;     // 16384 B packed A tile
static constexpr int BTILE = BN * BK;     //  8192 B packed B tile

// ---------------- fused pack kernel: int32 -> blocked int8 tiles -------------
// A tile (16 KB): [kg(4)][row(256)][16B]   wa: [M/256][NT][ATILE]
// B tile ( 8 KB): [kg(4)][col(128)][16B]   wb: [N/128][NT][BTILE] (transposed)
static constexpr int PX_BLOCKS = (int)((size_t)M * K / 16 / 256);  // 8192
static constexpr int PW_BLOCKS = (int)((size_t)N * K / 16 / 256);  // 4096

__device__ __forceinline__ unsigned pack4(i32x4 v) {
  return (unsigned)((v.x & 255) | ((v.y & 255) << 8) | ((v.z & 255) << 16) | (v.w << 24));
}

__global__ __launch_bounds__(256) void pack_kernel(const int* __restrict__ x,
                                                   const int* __restrict__ w,
                                                   unsigned char* __restrict__ wa,
                                                   unsigned char* __restrict__ wb) {
  if (blockIdx.x < PX_BLOCKS) {
    unsigned g = blockIdx.x * 256 + threadIdx.x;   // dest 16B granule, < M*K/16
    unsigned row = g & 255;
    unsigned kg  = (g >> 8) & 3;
    unsigned kt  = (g >> 10) & 63;
    unsigned br  = g >> 16;
    const int* src = x + ((size_t)(br * 256 + row) * K + kt * 64 + kg * 16);
    i32x4 v0 = *(const i32x4*)(src + 0);
    i32x4 v1 = *(const i32x4*)(src + 4);
    i32x4 v2 = *(const i32x4*)(src + 8);
    i32x4 v3 = *(const i32x4*)(src + 12);
    i32x4 d;
    d.x = (int)pack4(v0); d.y = (int)pack4(v1); d.z = (int)pack4(v2); d.w = (int)pack4(v3);
    *(i32x4*)(wa + (size_t)g * 16) = d;
  } else {
    unsigned g = (blockIdx.x - PX_BLOCKS) * 256 + threadIdx.x;  // < N*K/16
    unsigned col = g & 127;
    unsigned kg  = (g >> 7) & 3;
    unsigned kt  = (g >> 9) & 63;
    unsigned bn  = g >> 15;
    unsigned n   = bn * 128 + col;
    unsigned k0  = kt * 64 + kg * 16;
    const int* src = w + (size_t)k0 * N + n;
    i32x4 d;
#pragma unroll
    for (int j = 0; j < 4; ++j) {
      int b0 = src[(size_t)(j * 4 + 0) * N];
      int b1 = src[(size_t)(j * 4 + 1) * N];
      int b2 = src[(size_t)(j * 4 + 2) * N];
      int b3 = src[(size_t)(j * 4 + 3) * N];
      d[j] = (b0 & 255) | ((b1 & 255) << 8) | ((b2 & 255) << 16) | (b3 << 24);
    }
    *(i32x4*)(wb + (size_t)g * 16) = d;
  }
}

// -- GEMM: 256x128 block, 4 waves (2x2, wave 128x64, acc[4][2]), reg-staged ---
// dbuf LDS 48 KB -> 2 blocks/CU; VGPR ~200 -> 8 waves/CU total

__global__ __launch_bounds__(256, 2) void gemm_i8(const unsigned char* __restrict__ wa,
                                                  const unsigned char* __restrict__ wb,
                                                  const __half* __restrict__ bias,
                                                  const float* __restrict__ alphaP,
                                                  float* __restrict__ out) {
  __shared__ __align__(16) unsigned char As[2][ATILE];   // 32 KB
  __shared__ __align__(16) unsigned char Bs[2][BTILE];   // 16 KB -> 48 KB total

  const int tid  = threadIdx.x;
  const int lane = tid & 63;
  const int w    = tid >> 6;            // wave 0..3
  const int wr   = w >> 1, wc = w & 1;  // 2 x 2 grid; wave tile 128 x 64
  const int l31  = lane & 31;
  const int kgl  = lane >> 5;

  const int bc = blockIdx.x;            // 0..31 (fast: neighbors share A panel)
  const int br = blockIdx.y;            // 0..31

  const unsigned char* ga = wa + (size_t)br * NT * ATILE;
  const unsigned char* gb = wb + (size_t)bc * NT * BTILE;

  // reg staging: A 1024 granules -> 4/thread; B 512 granules -> 2/thread
  i32x4 s0, s1, s2, s3, s4, s5;

#define GLOAD(T) do {                                                \
    const i32x4* ap = (const i32x4*)(ga + (size_t)(T) * ATILE);      \
    const i32x4* bp = (const i32x4*)(gb + (size_t)(T) * BTILE);      \
    s0 = ap[tid]; s1 = ap[tid + 256];                                \
    s2 = ap[tid + 512]; s3 = ap[tid + 768];                          \
    s4 = bp[tid]; s5 = bp[tid + 256];                                \
  } while (0)

#define SWRITE(BUF) do {                                             \
    i32x4* aw = (i32x4*)&As[BUF][0];                                 \
    i32x4* bw = (i32x4*)&Bs[BUF][0];                                 \
    aw[tid] = s0; aw[tid + 256] = s1;                                \
    aw[tid + 512] = s2; aw[tid + 768] = s3;                          \
    bw[tid] = s4; bw[tid + 256] = s5;                                \
  } while (0)

  GLOAD(0);
  SWRITE(0);
  __syncthreads();

  i32x16 acc[4][2] = {};

  const int arow = wr * 128 + l31;      // A frag row base (per lane)
  const int bcol = wc * 64 + l31;       // B frag col base (per lane)

  for (int t = 0; t < NT; ++t) {
    const int cur = t & 1;
    if (t + 1 < NT) GLOAD(t + 1);       // issue early: latency hides under MFMA

    const unsigned char* Ab = &As[cur][0] + kgl * 4096;   // [kg][row(256)][16]
    const unsigned char* Bb = &Bs[cur][0] + kgl * 2048;   // [kg][col(128)][16]
#pragma unroll
    for (int kc = 0; kc < 2; ++kc) {    // kg = kc*2 + kgl
      const unsigned char* Ap = Ab + kc * 8192;
      const unsigned char* Bp = Bb + kc * 4096;
      i32x4 a0 = *(const i32x4*)(Ap + (arow +  0) * 16);
      i32x4 a1 = *(const i32x4*)(Ap + (arow + 32) * 16);
      i32x4 a2 = *(const i32x4*)(Ap + (arow + 64) * 16);
      i32x4 a3 = *(const i32x4*)(Ap + (arow + 96) * 16);
      i32x4 b0 = *(const i32x4*)(Bp + (bcol +  0) * 16);
      i32x4 b1 = *(const i32x4*)(Bp + (bcol + 32) * 16);
      acc[0][0] = __builtin_amdgcn_mfma_i32_32x32x32_i8(a0, b0, acc[0][0], 0, 0, 0);
      acc[0][1] = __builtin_amdgcn_mfma_i32_32x32x32_i8(a0, b1, acc[0][1], 0, 0, 0);
      acc[1][0] = __builtin_amdgcn_mfma_i32_32x32x32_i8(a1, b0, acc[1][0], 0, 0, 0);
      acc[1][1] = __builtin_amdgcn_mfma_i32_32x32x32_i8(a1, b1, acc[1][1], 0, 0, 0);
      acc[2][0] = __builtin_amdgcn_mfma_i32_32x32x32_i8(a2, b0, acc[2][0], 0, 0, 0);
      acc[2][1] = __builtin_amdgcn_mfma_i32_32x32x32_i8(a2, b1, acc[2][1], 0, 0, 0);
      acc[3][0] = __builtin_amdgcn_mfma_i32_32x32x32_i8(a3, b0, acc[3][0], 0, 0, 0);
      acc[3][1] = __builtin_amdgcn_mfma_i32_32x32x32_i8(a3, b1, acc[3][1], 0, 0, 0);
    }

    // fence: gload + frag reads + MFMAs above; vmcnt-wait + ds_write below
    __builtin_amdgcn_sched_barrier(0);
    if (t + 1 < NT) SWRITE(cur ^ 1);
    __syncthreads();
  }

  // epilogue: C/D layout col=lane&31, row=(r&3)+8*(r>>2)+4*(lane>>5)
  const float alpha = *alphaP;
  const int row0 = br * 256 + wr * 128 + 4 * kgl;
  const int col0 = bc * 128 + wc * 64 + l31;
#pragma unroll
  for (int ni = 0; ni < 2; ++ni) {
    const int col = col0 + ni * 32;
    const float bf = __half2float(bias[col]);
#pragma unroll
    for (int mi = 0; mi < 4; ++mi) {
#pragma unroll
      for (int r = 0; r < 16; ++r) {
        const int row = row0 + mi * 32 + (r & 3) + 8 * (r >> 2);
        out[(size_t)row * N + col] = ((float)acc[mi][ni][r] + bf) * alpha;
      }
    }
  }
#undef GLOAD
#undef SWRITE
}

extern "C" void kernel_launch(void* const* d_in, const int* in_sizes, int n_in,
                              void* d_out, int out_size, void* d_ws, size_t ws_size,
                              hipStream_t stream) {
  const int*    x     = (const int*)d_in[0];
  const int*    wgt   = (const int*)d_in[1];
  const __half* bias  = (const __half*)d_in[2];
  const float*  alpha = (const float*)d_in[3];
  float*        out   = (float*)d_out;

  // workspace: packed A (32 MB) + packed B (16 MB) = 48 MB
  unsigned char* wa = (unsigned char*)d_ws;
  unsigned char* wb = wa + (size_t)M * K;

  pack_kernel<<<PX_BLOCKS + PW_BLOCKS, 256, 0, stream>>>(x, wgt, wa, wb);

  dim3 grid(N / BN, M / BM);   // 32 x 32 = 1024 blocks, 2 resident/CU
  gemm_i8<<<grid, 256, 0, stream>>>(wa, wb, bias, alpha, out);
}